// Round 1
// baseline (436.451 us; speedup 1.0000x reference)
//
#include <hip/hip_runtime.h>

typedef __bf16 bf16x8 __attribute__((ext_vector_type(8)));
typedef float floatx4 __attribute__((ext_vector_type(4)));

static constexpr int ROW_IN  = 160;   // 64 scalars + 32*3 vectors
static constexpr int ROW_OUT = 160;   // 64 + 32*3

// constants (C_SV1*INV_SQRT3 == sqrt(1/128) == C_SS0; C_VS1*INV_SQRT3 == 1/8)
static constexpr float C_SS0_F    = 0.08838834764831845f; // sqrt(1/128)
static constexpr float C_VV0_I3_F = 0.07216878364870323f; // sqrt(1/64)/sqrt(3)
static constexpr float C_SV1_I3_F = 0.08838834764831845f; // sqrt(3/128)/sqrt(3)
static constexpr float C_VS1_I3_F = 0.125f;               // sqrt(3/64)/sqrt(3)

__device__ __forceinline__ floatx4 mfma16(bf16x8 a, bf16x8 b, floatx4 c) {
    return __builtin_amdgcn_mfma_f32_16x16x32_bf16(a, b, c, 0, 0, 0);
}

// A-frag layout (16x16x32): lane holds A[m=lane&15][k=quad*8+j], j=0..7
// B-frag layout:            lane holds B[k=quad*8+j][n=lane&15]
// C/D layout:               lane reg r holds D[row=quad*4+r][col=lane&15]
__global__ __launch_bounds__(256, 2)
void o3tp_kernel(const float* __restrict__ x1, const float* __restrict__ x2,
                 const float* __restrict__ Wss0, const float* __restrict__ Wvv0,
                 const float* __restrict__ Wsv1, const float* __restrict__ Wvs1,
                 const float* __restrict__ bias0, float* __restrict__ out, int n)
{
    const int lane = threadIdx.x & 63;
    const int m = lane & 15;           // output col within 16-tile / A-row
    const int q = lane >> 4;           // quad: k-slice (A/B) or row-group (C)

    // ---------- B fragments: built once per wave, live in VGPRs ----------
    bf16x8 Bss[2][4];   // Wss0 (K=64 -> 2 k-tiles) x (64 cols -> 4 col-tiles), raw
    bf16x8 Bvv[4];      // Wvv0 (K=32) x 4 col-tiles, raw (scale folded into d)
    bf16x8 Bsv[2][2];   // Wsv1 (K=64) x 2 col-tiles, scaled by C_SV1/sqrt3
    bf16x8 Bvs[2];      // Wvs1 (K=32) x 2 col-tiles, raw (scale folded into A)
#pragma unroll
    for (int kt = 0; kt < 2; ++kt)
#pragma unroll
        for (int ct = 0; ct < 4; ++ct)
#pragma unroll
            for (int j = 0; j < 8; ++j)
                Bss[kt][ct][j] = (__bf16)Wss0[(kt*32 + q*8 + j)*64 + ct*16 + m];
#pragma unroll
    for (int ct = 0; ct < 4; ++ct)
#pragma unroll
        for (int j = 0; j < 8; ++j)
            Bvv[ct][j] = (__bf16)Wvv0[(q*8 + j)*64 + ct*16 + m];
#pragma unroll
    for (int kt = 0; kt < 2; ++kt)
#pragma unroll
        for (int ct = 0; ct < 2; ++ct)
#pragma unroll
            for (int j = 0; j < 8; ++j)
                Bsv[kt][ct][j] = (__bf16)(Wsv1[(kt*32 + q*8 + j)*32 + ct*16 + m] * C_SV1_I3_F);
#pragma unroll
    for (int ct = 0; ct < 2; ++ct)
#pragma unroll
        for (int j = 0; j < 8; ++j)
            Bvs[ct][j] = (__bf16)Wvs1[(q*8 + j)*32 + ct*16 + m];

    float bias_r[4];
#pragma unroll
    for (int ct = 0; ct < 4; ++ct) bias_r[ct] = bias0[ct*16 + m];

    const floatx4 zero = {0.f, 0.f, 0.f, 0.f};

    const int n_tiles = n >> 4;  // n == 400000, divisible by 16
    const int wid     = blockIdx.x * (blockDim.x >> 6) + (threadIdx.x >> 6);
    const int n_waves = gridDim.x * (blockDim.x >> 6);

    for (int tile = wid; tile < n_tiles; tile += n_waves) {
        const int row0 = tile << 4;
        const float* __restrict__ xr = x1 + (size_t)(row0 + m) * ROW_IN;
        const float4 x2m = *(const float4*)(x2 + (size_t)(row0 + m) * 4);

        // ---- A fragments for s1 (raw and s2*C_SS0-scaled) ----
        bf16x8 a_s[2], a_ss[2];
        const float sscale = x2m.x * C_SS0_F;
#pragma unroll
        for (int kt = 0; kt < 2; ++kt) {
            const float4 f0 = *(const float4*)(xr + kt*32 + q*8);
            const float4 f1 = *(const float4*)(xr + kt*32 + q*8 + 4);
            const float v[8] = {f0.x, f0.y, f0.z, f0.w, f1.x, f1.y, f1.z, f1.w};
#pragma unroll
            for (int j = 0; j < 8; ++j) {
                a_s[kt][j]  = (__bf16)v[j];
                a_ss[kt][j] = (__bf16)(v[j] * sscale);
            }
        }

        // ---- v1 chunk: 8 u-values (u = q*8+j), 3 components each ----
        float c[24];
#pragma unroll
        for (int t = 0; t < 6; ++t) {
            const float4 f = *(const float4*)(xr + 64 + q*24 + t*4);
            c[t*4+0] = f.x; c[t*4+1] = f.y; c[t*4+2] = f.z; c[t*4+3] = f.w;
        }
        bf16x8 a_d, a_v0, a_v1, a_v2;
        const float gscale = x2m.x * C_VS1_I3_F;
#pragma unroll
        for (int j = 0; j < 8; ++j) {
            const float d = (c[3*j+0]*x2m.y + c[3*j+1]*x2m.z + c[3*j+2]*x2m.w) * C_VV0_I3_F;
            a_d[j]  = (__bf16)d;
            a_v0[j] = (__bf16)(c[3*j+0] * gscale);
            a_v1[j] = (__bf16)(c[3*j+1] * gscale);
            a_v2[j] = (__bf16)(c[3*j+2] * gscale);
        }

        // ---- MFMAs: all K fully useful, 22 per tile ----
        floatx4 acc0[4], accT[2], accG[3][2];
#pragma unroll
        for (int ct = 0; ct < 4; ++ct) {
            acc0[ct] = mfma16(a_ss[0], Bss[0][ct], zero);
            acc0[ct] = mfma16(a_ss[1], Bss[1][ct], acc0[ct]);
            acc0[ct] = mfma16(a_d,     Bvv[ct],    acc0[ct]);
        }
#pragma unroll
        for (int ct = 0; ct < 2; ++ct) {
            accT[ct] = mfma16(a_s[0], Bsv[0][ct], zero);
            accT[ct] = mfma16(a_s[1], Bsv[1][ct], accT[ct]);
            accG[0][ct] = mfma16(a_v0, Bvs[ct], zero);
            accG[1][ct] = mfma16(a_v1, Bvs[ct], zero);
            accG[2][ct] = mfma16(a_v2, Bvs[ct], zero);
        }

        // ---- epilogue ----
#pragma unroll
        for (int r = 0; r < 4; ++r) {
            const int row = row0 + q*4 + r;
            float* __restrict__ orow = out + (size_t)row * ROW_OUT;
            const float4 x2r = *(const float4*)(x2 + (size_t)row * 4);
#pragma unroll
            for (int ct = 0; ct < 4; ++ct)
                orow[ct*16 + m] = acc0[ct][r] + bias_r[ct];
#pragma unroll
            for (int ct = 0; ct < 2; ++ct) {
                const int w = ct*16 + m;
                const float t = accT[ct][r];
                orow[64 + 3*w + 0] = x2r.y * t + accG[0][ct][r];
                orow[64 + 3*w + 1] = x2r.z * t + accG[1][ct][r];
                orow[64 + 3*w + 2] = x2r.w * t + accG[2][ct][r];
            }
        }
    }
}

extern "C" void kernel_launch(void* const* d_in, const int* in_sizes, int n_in,
                              void* d_out, int out_size, void* d_ws, size_t ws_size,
                              hipStream_t stream) {
    const float* x1    = (const float*)d_in[0];
    const float* x2    = (const float*)d_in[1];
    const float* Wss0  = (const float*)d_in[2];
    const float* Wvv0  = (const float*)d_in[3];
    const float* Wsv1  = (const float*)d_in[4];
    const float* Wvs1  = (const float*)d_in[5];
    const float* bias0 = (const float*)d_in[6];
    float* out = (float*)d_out;
    const int n = in_sizes[0] / ROW_IN;   // 400000

    // 512 blocks x 4 waves = 2048 waves = full residency at 2 waves/SIMD;
    // each wave grid-strides ~12 tiles, amortizing the one-time B-fragment build.
    dim3 grid(512), block(256);
    hipLaunchKernelGGL(o3tp_kernel, grid, block, 0, stream,
                       x1, x2, Wss0, Wvv0, Wsv1, Wvs1, bias0, out, n);
}

// Round 2
// 435.745 us; speedup vs baseline: 1.0016x; 1.0016x over previous
//
#include <hip/hip_runtime.h>

typedef __bf16 bf16x8 __attribute__((ext_vector_type(8)));
typedef float floatx4 __attribute__((ext_vector_type(4)));

static constexpr int ROW_IN  = 160;   // 64 scalars + 32*3 vectors
static constexpr int ROW_OUT = 160;   // 64 + 32*3
static constexpr int LDS_STRIDE = 164; // +4 pad: 160 % 32 == 0 would alias all rows to one bank group

// constants (C_SV1*INV_SQRT3 == sqrt(1/128) == C_SS0; C_VS1*INV_SQRT3 == 1/8)
static constexpr float C_SS0_F    = 0.08838834764831845f; // sqrt(1/128)
static constexpr float C_VV0_I3_F = 0.07216878364870323f; // sqrt(1/64)/sqrt(3)
static constexpr float C_SV1_I3_F = 0.08838834764831845f; // sqrt(3/128)/sqrt(3)
static constexpr float C_VS1_I3_F = 0.125f;               // sqrt(3/64)/sqrt(3)

__device__ __forceinline__ floatx4 mfma16(bf16x8 a, bf16x8 b, floatx4 c) {
    return __builtin_amdgcn_mfma_f32_16x16x32_bf16(a, b, c, 0, 0, 0);
}

// A-frag layout (16x16x32): lane holds A[m=lane&15][k=quad*8+j], j=0..7
// B-frag layout:            lane holds B[k=quad*8+j][n=lane&15]
// C/D layout:               lane reg r holds D[row=quad*4+r][col=lane&15]
__global__ __launch_bounds__(256, 2)
void o3tp_kernel(const float* __restrict__ x1, const float* __restrict__ x2,
                 const float* __restrict__ Wss0, const float* __restrict__ Wvv0,
                 const float* __restrict__ Wsv1, const float* __restrict__ Wvs1,
                 const float* __restrict__ bias0, float* __restrict__ out, int n)
{
    // wave-private staging buffer: 16 rows x 164 floats (10496 B/wave, 42 KB/block)
    __shared__ float lds[4][16 * LDS_STRIDE];
    float* __restrict__ tl = lds[threadIdx.x >> 6];

    const int lane = threadIdx.x & 63;
    const int m = lane & 15;           // output col within 16-tile / A-row
    const int q = lane >> 4;           // quad: k-slice (A/B) or row-group (C)

    // ---------- B fragments: built once per wave, live in VGPRs ----------
    bf16x8 Bss[2][4];   // Wss0 (K=64 -> 2 k-tiles) x (64 cols -> 4 col-tiles)
    bf16x8 Bvv[4];      // Wvv0 (K=32) x 4 col-tiles (scale folded into d)
    bf16x8 Bsv[2][2];   // Wsv1 (K=64) x 2 col-tiles, scaled by C_SV1/sqrt3
    bf16x8 Bvs[2];      // Wvs1 (K=32) x 2 col-tiles (scale folded into A)
#pragma unroll
    for (int kt = 0; kt < 2; ++kt)
#pragma unroll
        for (int ct = 0; ct < 4; ++ct)
#pragma unroll
            for (int j = 0; j < 8; ++j)
                Bss[kt][ct][j] = (__bf16)Wss0[(kt*32 + q*8 + j)*64 + ct*16 + m];
#pragma unroll
    for (int ct = 0; ct < 4; ++ct)
#pragma unroll
        for (int j = 0; j < 8; ++j)
            Bvv[ct][j] = (__bf16)Wvv0[(q*8 + j)*64 + ct*16 + m];
#pragma unroll
    for (int kt = 0; kt < 2; ++kt)
#pragma unroll
        for (int ct = 0; ct < 2; ++ct)
#pragma unroll
            for (int j = 0; j < 8; ++j)
                Bsv[kt][ct][j] = (__bf16)(Wsv1[(kt*32 + q*8 + j)*32 + ct*16 + m] * C_SV1_I3_F);
#pragma unroll
    for (int ct = 0; ct < 2; ++ct)
#pragma unroll
        for (int j = 0; j < 8; ++j)
            Bvs[ct][j] = (__bf16)Wvs1[(q*8 + j)*32 + ct*16 + m];

    float bias_r[4];
#pragma unroll
    for (int ct = 0; ct < 4; ++ct) bias_r[ct] = bias0[ct*16 + m];

    const floatx4 zero = {0.f, 0.f, 0.f, 0.f};

    const int n_tiles = n >> 4;  // 400000/16 = 25000
    const int wid     = blockIdx.x * (blockDim.x >> 6) + (threadIdx.x >> 6);
    const int n_waves = gridDim.x * (blockDim.x >> 6);

    for (int tile = wid; tile < n_tiles; tile += n_waves) {
        const int row0 = tile << 4;

        // ---- stage 1: coalesced global -> LDS (16x160 fp32 = one contiguous 10240B block) ----
        asm volatile("" ::: "memory");   // don't let staging writes sink past prior LDS reads
        const float* __restrict__ src = x1 + (size_t)row0 * ROW_IN;
        float4 v[10];
#pragma unroll
        for (int it = 0; it < 10; ++it)
            v[it] = *(const float4*)(src + (it*64 + lane)*4);
        const float4 x2m = *(const float4*)(x2 + (size_t)(row0 + m) * 4);
#pragma unroll
        for (int it = 0; it < 10; ++it) {
            const int f   = it*64 + lane;
            const int row = f / 40;              // 40 float4 per 160-float row
            const int col = f*4 - row*ROW_IN;
            *(float4*)(tl + row*LDS_STRIDE + col) = v[it];
        }
        asm volatile("s_waitcnt lgkmcnt(0)" ::: "memory");  // cross-lane LDS visibility

        // ---- stage 2: A-fragments from LDS ----
        const float* __restrict__ xr = tl + m * LDS_STRIDE;
        bf16x8 a_s[2], a_ss[2];
        const float sscale = x2m.x * C_SS0_F;
#pragma unroll
        for (int kt = 0; kt < 2; ++kt) {
            const float4 f0 = *(const float4*)(xr + kt*32 + q*8);
            const float4 f1 = *(const float4*)(xr + kt*32 + q*8 + 4);
            const float vv[8] = {f0.x, f0.y, f0.z, f0.w, f1.x, f1.y, f1.z, f1.w};
#pragma unroll
            for (int j = 0; j < 8; ++j) {
                a_s[kt][j]  = (__bf16)vv[j];
                a_ss[kt][j] = (__bf16)(vv[j] * sscale);
            }
        }
        float c[24];
#pragma unroll
        for (int t = 0; t < 6; ++t) {
            const float4 f = *(const float4*)(xr + 64 + q*24 + t*4);
            c[t*4+0] = f.x; c[t*4+1] = f.y; c[t*4+2] = f.z; c[t*4+3] = f.w;
        }
        bf16x8 a_d, a_v0, a_v1, a_v2;
        const float gscale = x2m.x * C_VS1_I3_F;
#pragma unroll
        for (int j = 0; j < 8; ++j) {
            const float d = (c[3*j+0]*x2m.y + c[3*j+1]*x2m.z + c[3*j+2]*x2m.w) * C_VV0_I3_F;
            a_d[j]  = (__bf16)d;
            a_v0[j] = (__bf16)(c[3*j+0] * gscale);
            a_v1[j] = (__bf16)(c[3*j+1] * gscale);
            a_v2[j] = (__bf16)(c[3*j+2] * gscale);
        }

        // ---- stage 3: MFMAs (22, all K useful) ----
        floatx4 acc0[4], accT[2], accG[3][2];
#pragma unroll
        for (int ct = 0; ct < 4; ++ct) {
            acc0[ct] = mfma16(a_ss[0], Bss[0][ct], zero);
            acc0[ct] = mfma16(a_ss[1], Bss[1][ct], acc0[ct]);
            acc0[ct] = mfma16(a_d,     Bvv[ct],    acc0[ct]);
        }
#pragma unroll
        for (int ct = 0; ct < 2; ++ct) {
            accT[ct] = mfma16(a_s[0], Bsv[0][ct], zero);
            accT[ct] = mfma16(a_s[1], Bsv[1][ct], accT[ct]);
            accG[0][ct] = mfma16(a_v0, Bvs[ct], zero);
            accG[1][ct] = mfma16(a_v1, Bvs[ct], zero);
            accG[2][ct] = mfma16(a_v2, Bvs[ct], zero);
        }

        // ---- stage 4: epilogue into LDS (reuse buffer; A-frag reads already drained via MFMA deps) ----
        asm volatile("" ::: "memory");
#pragma unroll
        for (int r = 0; r < 4; ++r) {
            const int rr = q*4 + r;
            // x2 of row rr held by lane rr (its m == rr)
            const float xy = __shfl(x2m.y, rr, 64);
            const float xz = __shfl(x2m.z, rr, 64);
            const float xw = __shfl(x2m.w, rr, 64);
            float* __restrict__ orow = tl + rr * LDS_STRIDE;
#pragma unroll
            for (int ct = 0; ct < 4; ++ct)
                orow[ct*16 + m] = acc0[ct][r] + bias_r[ct];
#pragma unroll
            for (int ct = 0; ct < 2; ++ct) {
                const int w = ct*16 + m;
                const float t = accT[ct][r];
                orow[64 + 3*w + 0] = xy * t + accG[0][ct][r];
                orow[64 + 3*w + 1] = xz * t + accG[1][ct][r];
                orow[64 + 3*w + 2] = xw * t + accG[2][ct][r];
            }
        }
        asm volatile("s_waitcnt lgkmcnt(0)" ::: "memory");  // cross-lane LDS visibility

        // ---- stage 5: coalesced LDS -> global (contiguous 10240B output tile) ----
        float* __restrict__ dst = out + (size_t)row0 * ROW_OUT;
#pragma unroll
        for (int it = 0; it < 10; ++it) {
            const int f   = it*64 + lane;
            const int row = f / 40;
            const int col = f*4 - row*ROW_OUT;
            const float4 vv = *(const float4*)(tl + row*LDS_STRIDE + col);
            *(float4*)(dst + f*4) = vv;
        }
    }
}

extern "C" void kernel_launch(void* const* d_in, const int* in_sizes, int n_in,
                              void* d_out, int out_size, void* d_ws, size_t ws_size,
                              hipStream_t stream) {
    const float* x1    = (const float*)d_in[0];
    const float* x2    = (const float*)d_in[1];
    const float* Wss0  = (const float*)d_in[2];
    const float* Wvv0  = (const float*)d_in[3];
    const float* Wsv1  = (const float*)d_in[4];
    const float* Wvs1  = (const float*)d_in[5];
    const float* bias0 = (const float*)d_in[6];
    float* out = (float*)d_out;
    const int n = in_sizes[0] / ROW_IN;   // 400000

    // 512 blocks x 4 waves = 2048 waves (8/CU at 2 blocks/CU); ~12 tiles/wave
    // amortizes the one-time B-fragment build.
    dim3 grid(512), block(256);
    hipLaunchKernelGGL(o3tp_kernel, grid, block, 0, stream,
                       x1, x2, Wss0, Wvv0, Wsv1, Wvs1, bias0, out, n);
}